// Round 10
// baseline (192.753 us; speedup 1.0000x reference)
//
#include <hip/hip_runtime.h>
#include <math.h>

#define BN_EPS 1e-5
#define SIGMA 1.0f

typedef double f64x4 __attribute__((ext_vector_type(4)));

// ============ conv1 via fp64 MFMA implicit GEMM (v4: 128m x 32n block, 8 blocks/CU) ========
// C[m=pixel][n=oc] = sum_k A[m][k] B[k][n], k = (kh,kw) major, ic minor
// grid 1024 = ksp(8: 16 ic) x b(8) x ng(2: 32 oc) x mt(8: 4 oh rows); block 256 = 4 waves
// wave wv = one output row (oh = 4*mt + wv), 32 ow x 32 oc = 2x2 mfma_f64_16x16x4 frags.
// B in LDS [khw][icb][n(32)][lg(4)] = 18.4 KB  ->  8 blocks/CU = 32 waves/CU (2x r9).
// Per-wave instruction stream identical to r9 (144 MFMAs, 72 A-loads) -> part1 bit-identical.
// D row map probed at runtime (r7-verified).
__global__ __launch_bounds__(256, 8) void conv1_mfma_kernel(
    const float* __restrict__ in, const float* __restrict__ w1,
    float* __restrict__ part)
{
    __shared__ float swt[4608];   // weights; reused as output-transpose buffer (32 x 132)

    int bid = blockIdx.x;
    int mt  = bid & 7;             // oh0 = 4*mt
    int ng  = (bid >> 3) & 1;      // oc half
    int b   = (bid >> 4) & 7;
    int ksp = bid >> 7;            // 16 ic per split

    int tid = threadIdx.x;
    int l   = tid & 63;
    int wv  = tid >> 6;            // 0..3 = output row within block
    int lc  = l & 15;
    int lg  = l >> 4;              // 0..3

    // ---- D-layout probe: A[m][k] = m, B = delta(k==0,n==0) => D[m][0] = m.
    double ap = (double)lc;
    double bp = (l == 0) ? 1.0 : 0.0;
    f64x4 dp = {0., 0., 0., 0.};
    dp = __builtin_amdgcn_mfma_f64_16x16x4f64(ap, bp, dp, 0, 0, 0);
    int row0[4];
    #pragma unroll
    for (int r = 0; r < 4; ++r)
        row0[r] = ((int)__shfl(dp[r], (l & 0x30), 64)) & 15;

    // ---- stage weights: swt[((khw*4+icb)*32 + nn)*4 + g] = w1[ng*32+nn][ksp*16+icb*4+g][khw]
    for (int i = tid; i < 4608; i += 256) {
        int g   = i & 3;
        int nn  = (i >> 2) & 31;
        int kic = i >> 7;           // khw*4 + icb
        int khw = kic >> 2;
        int icb = kic & 3;
        swt[i] = w1[((ng * 32 + nn) * 128 + ksp * 16 + icb * 4 + g) * 9 + khw];
    }
    __syncthreads();

    f64x4 d00 = {0., 0., 0., 0.}, d01 = {0., 0., 0., 0.};
    f64x4 d10 = {0., 0., 0., 0.}, d11 = {0., 0., 0., 0.};

    // A addressing: channel = ksp*16 + icb*4 + lg; wave's output row oh = 4*mt + wv
    const float* cb = in + (size_t)(b * 128 + ksp * 16 + lg) * 4096;
    int r0 = 8 * mt + 2 * wv - 1;                       // ih for kh==0 (>= -1; +kh+... <= 63)
    const float* pbase = cb + (ptrdiff_t)(r0 * 64 + 2 * lc - 1);
    bool c0ok = (lc != 0);

    // B per-lane base: nn = lc (+16 for b1), k-slot = lg
    const float* pB = swt + lc * 4 + lg;

    float a0A[12], a1A[12], a0B[12], a1B[12];

#define LOAD_KH(KH, A0, A1)                                                   \
    {                                                                         \
        const bool rowok = ((KH) > 0) || (r0 >= 0);                           \
        _Pragma("unroll")                                                     \
        for (int icb = 0; icb < 4; ++icb) {                                   \
            _Pragma("unroll")                                                 \
            for (int c = 0; c < 3; ++c) {                                     \
                const int off = icb * 16384 + (KH) * 64 + c;                  \
                bool ok0 = rowok && ((c > 0) || c0ok);                        \
                const float* q0 = ok0 ? (pbase + off) : cb;                   \
                float f0 = *q0;                                               \
                A0[icb * 3 + c] = ok0 ? f0 : 0.f;                             \
                const float* q1 = rowok ? (pbase + off + 32) : cb;            \
                float f1 = *q1;                                               \
                A1[icb * 3 + c] = rowok ? f1 : 0.f;                           \
            }                                                                 \
        }                                                                     \
    }

#define MFMA_KH(KH, A0, A1)                                                   \
    {                                                                         \
        _Pragma("unroll")                                                     \
        for (int kw = 0; kw < 3; ++kw) {                                      \
            const int khw = (KH) * 3 + kw;                                    \
            _Pragma("unroll")                                                 \
            for (int icb = 0; icb < 4; ++icb) {                               \
                double a0 = (double)A0[icb * 3 + kw];                         \
                double a1 = (double)A1[icb * 3 + kw];                         \
                const int offB = (khw * 4 + icb) * 128;                       \
                double b0 = (double)pB[offB];                                 \
                double b1 = (double)pB[offB + 64];                            \
                d00 = __builtin_amdgcn_mfma_f64_16x16x4f64(a0, b0, d00, 0, 0, 0); \
                d01 = __builtin_amdgcn_mfma_f64_16x16x4f64(a0, b1, d01, 0, 0, 0); \
                d10 = __builtin_amdgcn_mfma_f64_16x16x4f64(a1, b0, d10, 0, 0, 0); \
                d11 = __builtin_amdgcn_mfma_f64_16x16x4f64(a1, b1, d11, 0, 0, 0); \
            }                                                                 \
        }                                                                     \
    }

    LOAD_KH(0, a0A, a1A);
    LOAD_KH(1, a0B, a1B);
    MFMA_KH(0, a0A, a1A);
    LOAD_KH(2, a0A, a1A);
    MFMA_KH(1, a0B, a1B);
    MFMA_KH(2, a0A, a1A);

#undef LOAD_KH
#undef MFMA_KH

    __syncthreads();   // weights no longer needed; reuse swt as transpose buffer
    float* so = swt;   // 32 oc x 132 = 4224 floats <= 4608
    // D frag (lg, r): ow = mi*16 + row0[r], oc = lc (d*0) / lc+16 (d*1); wave row = wv
    #pragma unroll
    for (int mi = 0; mi < 2; ++mi) {
        f64x4 v0 = mi ? d10 : d00;   // oc0 = lc
        f64x4 v1 = mi ? d11 : d01;   // oc0 = lc + 16
        #pragma unroll
        for (int r = 0; r < 4; ++r) {
            int m = wv * 32 + mi * 16 + row0[r];
            so[lc * 132 + m]        = (float)v0[r];
            so[(lc + 16) * 132 + m] = (float)v1[r];
        }
    }
    __syncthreads();
    int oh0 = 4 * mt;
    for (int i = tid; i < 4096; i += 256) {
        int ocl = i >> 7;            // 0..31
        int m   = i & 127;           // row (m>>5) x ow (m&31)
        part[(size_t)ksp * 524288 +
             ((b * 64 + ng * 32 + ocl) * 32 + oh0 + (m >> 5)) * 32 + (m & 31)] =
            so[ocl * 132 + m];
    }
}

// ============ conv2 partial, FUSED with conv1-combine (sum 8 partials + BN1 + ReLU) =========
// grid 512 = isp(16: 4 ic) x b(8) x ocg(4); block 256 = full 16x16 spatial
__global__ __launch_bounds__(256) void conv2_partial_kernel(
    const float* __restrict__ part1,
    const float* __restrict__ g1, const float* __restrict__ be1,
    const float* __restrict__ mn1, const float* __restrict__ vr1,
    const float* __restrict__ w,
    float* __restrict__ part)
{
    __shared__ float tin[4][33][36];
    __shared__ float twt[4][9][8];
    __shared__ double sinv[4], ssh[4];

    int bid = blockIdx.x;
    int ocg = bid & 3;
    int b   = (bid >> 2) & 7;
    int isp = bid >> 5;

    int tid = threadIdx.x;
    int ow  = tid & 15;
    int oh  = tid >> 4;

    if (tid < 4) {
        int ch = isp * 4 + tid;
        double inv = (double)g1[ch] / sqrt((double)vr1[ch] + BN_EPS);
        sinv[tid] = inv;
        ssh[tid]  = (double)be1[ch] - (double)mn1[ch] * inv;
    }
    __syncthreads();

    for (int lin = tid; lin < 4 * 33 * 34; lin += 256) {
        int c   = lin % 34;
        int t2  = lin / 34;
        int rr  = t2 % 33;
        int icc = t2 / 33;
        int ih  = rr - 1;
        int iw  = c - 1;
        float v = 0.f;
        if ((unsigned)ih < 32u && (unsigned)iw < 32u) {
            int ch  = isp * 4 + icc;
            int idx = ((b * 64 + ch) * 32 + ih) * 32 + iw;
            double s = 0.0;
            #pragma unroll
            for (int p = 0; p < 8; ++p) s += (double)part1[idx + p * 524288];
            double o = s * sinv[icc] + ssh[icc];
            v = fmaxf((float)o, 0.f);
        }
        tin[icc][rr][c] = v;
    }
    for (int i = tid; i < 288; i += 256) {
        int j   = i & 7;
        int k   = (i >> 3) % 9;
        int icc = i / 72;
        twt[icc][k][j] = w[(ocg * 8 + j) * 576 + (isp * 4 + icc) * 9 + k];
    }
    __syncthreads();

    double acc[8];
    #pragma unroll
    for (int j = 0; j < 8; ++j) acc[j] = 0.0;

    for (int icc = 0; icc < 4; ++icc) {
        double xv[9];
        #pragma unroll
        for (int kh = 0; kh < 3; ++kh)
            #pragma unroll
            for (int kw = 0; kw < 3; ++kw)
                xv[kh * 3 + kw] = (double)tin[icc][2 * oh + kh][2 * ow + kw];
        #pragma unroll
        for (int k = 0; k < 9; ++k) {
            float4 wa = *(const float4*)&twt[icc][k][0];
            float4 wb = *(const float4*)&twt[icc][k][4];
            acc[0] = fma(xv[k], (double)wa.x, acc[0]);
            acc[1] = fma(xv[k], (double)wa.y, acc[1]);
            acc[2] = fma(xv[k], (double)wa.z, acc[2]);
            acc[3] = fma(xv[k], (double)wa.w, acc[3]);
            acc[4] = fma(xv[k], (double)wb.x, acc[4]);
            acc[5] = fma(xv[k], (double)wb.y, acc[5]);
            acc[6] = fma(xv[k], (double)wb.z, acc[6]);
            acc[7] = fma(xv[k], (double)wb.w, acc[7]);
        }
    }
    int obase = ((b * 32 + ocg * 8) * 16 + oh) * 16 + ow;
    #pragma unroll
    for (int j = 0; j < 8; ++j)
        part[isp * 65536 + obase + j * 256] = (float)acc[j];
}

// ============ conv2 combine + BN + ReLU + spatial mean -> ybar[256] ============
__global__ __launch_bounds__(256) void conv2_combine_ybar_kernel(
    const float* __restrict__ part,
    const float* __restrict__ g, const float* __restrict__ be,
    const float* __restrict__ mn, const float* __restrict__ vr,
    double* __restrict__ ybar)
{
    __shared__ double sm[4];
    int j  = blockIdx.x;             // j = b*32 + oc
    int oc = j & 31;
    int t  = threadIdx.x;
    int idx = j * 256 + t;
    double s = 0.0;
    #pragma unroll
    for (int p = 0; p < 16; ++p) s += (double)part[idx + p * 65536];
    double inv = (double)g[oc] / sqrt((double)vr[oc] + BN_EPS);
    double o = s * inv + ((double)be[oc] - (double)mn[oc] * inv);
    double v = fmax(o, 0.0);
    #pragma unroll
    for (int off = 32; off > 0; off >>= 1) v += __shfl_down(v, off, 64);
    if ((t & 63) == 0) sm[t >> 6] = v;
    __syncthreads();
    if (t == 0) ybar[j] = (sm[0] + sm[1] + sm[2] + sm[3]) * (1.0 / 256.0);
}

// ============ centers: conv3(1x1)+BN folded with the spatial mean, fp64 ============
__global__ __launch_bounds__(64) void centers_kernel(
    const double* __restrict__ ybar, const float* __restrict__ w3,
    const float* __restrict__ g, const float* __restrict__ be,
    const float* __restrict__ mn, const float* __restrict__ vr,
    double* __restrict__ cen_ws, float* __restrict__ cen_out)
{
    int t = threadIdx.x;
    if (t < 48) {
        int b = t / 6;
        int k = t % 6;
        double acc = 0.0;
        for (int ic = 0; ic < 32; ++ic) acc = fma((double)w3[k * 32 + ic], ybar[b * 32 + ic], acc);
        double inv = (double)g[k] / sqrt((double)vr[k] + BN_EPS);
        double c = acc * inv + ((double)be[k] - (double)mn[k] * inv);
        cen_ws[t]  = c;
        cen_out[t] = (float)c;
    }
}

// ============ quantization: fp64 dist/argmin, fp32 softmax; float4 I/O ============
__global__ __launch_bounds__(256) void quant_kernel(
    const float* __restrict__ x, const double* __restrict__ centers,
    float* __restrict__ qbar, float* __restrict__ qsoft,
    float* __restrict__ qhard, float* __restrict__ sym)
{
    int vid = blockIdx.x * 256 + threadIdx.x;   // float4 index; 2^17 vecs per batch
    int b = vid >> 17;

    double c[6];
    float cf[6];
    #pragma unroll
    for (int k = 0; k < 6; ++k) { c[k] = centers[b * 6 + k]; cf[k] = (float)c[k]; }

    float4 xv = ((const float4*)x)[vid];
    float xs[4] = {xv.x, xv.y, xv.z, xv.w};
    float r_bar[4], r_soft[4], r_hard[4], r_sym[4];

    #pragma unroll
    for (int i = 0; i < 4; ++i) {
        double xx = (double)xs[i];
        double d[6];
        double dmin = 1e300;
        int amin = 0;
        #pragma unroll
        for (int k = 0; k < 6; ++k) {
            double t = xx - c[k];
            d[k] = t * t;
            if (d[k] < dmin) { dmin = d[k]; amin = k; }
        }
        float se = 0.f, sw = 0.f;
        #pragma unroll
        for (int k = 0; k < 6; ++k) {
            float e = __expf(SIGMA * (float)(dmin - d[k]));
            se += e;
            sw += e * cf[k];
        }
        float qs = sw / se;
        float qh = cf[amin];
        r_soft[i] = qs;
        r_hard[i] = qh;
        r_bar[i]  = qh;
        r_sym[i]  = (float)amin;
    }

    ((float4*)qbar)[vid]  = make_float4(r_bar[0],  r_bar[1],  r_bar[2],  r_bar[3]);
    ((float4*)qsoft)[vid] = make_float4(r_soft[0], r_soft[1], r_soft[2], r_soft[3]);
    ((float4*)qhard)[vid] = make_float4(r_hard[0], r_hard[1], r_hard[2], r_hard[3]);
    ((float4*)sym)[vid]   = make_float4(r_sym[0],  r_sym[1],  r_sym[2],  r_sym[3]);
}

extern "C" void kernel_launch(void* const* d_in, const int* in_sizes, int n_in,
                              void* d_out, int out_size, void* d_ws, size_t ws_size,
                              hipStream_t stream) {
    const float* x  = (const float*)d_in[0];
    const float* cf = (const float*)d_in[1];
    const float* w1 = (const float*)d_in[2];
    const float* g1 = (const float*)d_in[3];
    const float* b1 = (const float*)d_in[4];
    const float* m1 = (const float*)d_in[5];
    const float* v1 = (const float*)d_in[6];
    const float* w2 = (const float*)d_in[7];
    const float* g2 = (const float*)d_in[8];
    const float* b2 = (const float*)d_in[9];
    const float* m2 = (const float*)d_in[10];
    const float* v2 = (const float*)d_in[11];
    const float* w3 = (const float*)d_in[12];
    const float* g3 = (const float*)d_in[13];
    const float* b3 = (const float*)d_in[14];
    const float* m3 = (const float*)d_in[15];
    const float* v3 = (const float*)d_in[16];

    const int NELEM = 8 * 128 * 64 * 64;      // 4,194,304
    float* out   = (float*)d_out;
    float* qbar  = out;
    float* qsoft = out + (size_t)NELEM;
    float* qhard = out + (size_t)2 * NELEM;
    float* sym   = out + (size_t)3 * NELEM;
    float* cen_o = out + (size_t)4 * NELEM;

    char* ws = (char*)d_ws;
    float*  part1 = (float*)(ws);                        // 8 x 524288 f32 = 16 MB
    float*  part2 = (float*)(ws + 16777216);             // 16 x 65536 f32 = 4 MB
    double* yb    = (double*)(ws + 20971520);            // 256 f64
    double* cen   = (double*)(ws + 20973568);            // 48 f64   (~21 MB total)

    conv1_mfma_kernel<<<1024, 256, 0, stream>>>(cf, w1, part1);
    conv2_partial_kernel<<<512, 256, 0, stream>>>(part1, g1, b1, m1, v1, w2, part2);
    conv2_combine_ybar_kernel<<<256, 256, 0, stream>>>(part2, g2, b2, m2, v2, yb);
    centers_kernel<<<1, 64, 0, stream>>>(yb, w3, g3, b3, m3, v3, cen, cen_o);
    quant_kernel<<<NELEM / 4 / 256, 256, 0, stream>>>(x, cen, qbar, qsoft, qhard, sym);
}

// Round 11
// 187.964 us; speedup vs baseline: 1.0255x; 1.0255x over previous
//
#include <hip/hip_runtime.h>
#include <math.h>

#define BN_EPS 1e-5
#define SIGMA 1.0f

typedef double f64x4 __attribute__((ext_vector_type(4)));

// ============ conv1 HYBRID: scalar-VALU blocks + fp64-MFMA blocks co-resident ============
// Slices isp 0..3: r1-proven scalar path (VALU fp64 FMA).  Slices 4..7: r8-proven MFMA path.
// type = (bid>>3)&1 so XCD round-robin (bid%8) deals BOTH types onto every XCD -> each CU
// hosts ~2 scalar + 2 MFMA blocks; VALU work and MFMA-pipe work overlap (separate pipes).
// Per-path code byte-identical to its proven round -> part1 slices bit-identical.
__global__ __launch_bounds__(256, 4) void conv1_hybrid_kernel(
    const float* __restrict__ in, const float* __restrict__ w1,
    float* __restrict__ part)
{
    __shared__ double smem_d[4608];            // union: scalar wlds[1152] f64 / mfma swt[9216] f32

    int bid  = blockIdx.x;
    int typ  = (bid >> 3) & 1;                 // alternate type every 8 bids (one XCD sweep)
    int bid2 = ((bid >> 4) << 3) | (bid & 7);  // 0..511 within type
    int tid  = threadIdx.x;

    if (typ == 0) {
        // ================= scalar path (r1): isp 0..3, 16 ic each =================
        double* wlds = smem_d;                 // [ic(16)][k(9)][j(8)]
        int oht = bid2 & 1;
        int b   = (bid2 >> 1) & 7;
        int isp = (bid2 >> 4) & 3;             // slices 0..3
        int ocg = bid2 >> 6;

        int ow  = tid & 31;
        int ohp = tid >> 5;                    // 0..7
        int oh0 = oht * 16 + ohp * 2;
        int ih0 = 2 * oh0 - 1;
        int iw0 = 2 * ow - 1;

        for (int i = tid; i < 1152; i += 256) {
            int j  = i & 7;
            int t  = i >> 3;
            int k  = t % 9;
            int ic = t / 9;
            wlds[i] = (double)w1[((ocg * 8 + j) * 128 + isp * 16 + ic) * 9 + k];
        }
        __syncthreads();

        double acc0[8], acc1[8];
        #pragma unroll
        for (int j = 0; j < 8; ++j) { acc0[j] = 0.0; acc1[j] = 0.0; }

        bool rowok[5], colok[3];
        #pragma unroll
        for (int t = 0; t < 5; ++t) rowok[t] = (ih0 + t) >= 0;
        #pragma unroll
        for (int t = 0; t < 3; ++t) colok[t] = (iw0 + t) >= 0;

        const float* base0 = in + ((size_t)(b * 128 + isp * 16) * 64 + ih0) * 64 + iw0;

        float cur[15];
        #pragma unroll
        for (int t = 0; t < 5; ++t)
            #pragma unroll
            for (int kw = 0; kw < 3; ++kw)
                cur[t * 3 + kw] = (rowok[t] && colok[kw]) ? base0[t * 64 + kw] : 0.f;

        for (int ic = 0; ic < 16; ++ic) {
            float nxt[15];
            if (ic + 1 < 16) {
                const float* basen = base0 + (size_t)(ic + 1) * 4096;
                #pragma unroll
                for (int t = 0; t < 5; ++t)
                    #pragma unroll
                    for (int kw = 0; kw < 3; ++kw)
                        nxt[t * 3 + kw] = (rowok[t] && colok[kw]) ? basen[t * 64 + kw] : 0.f;
            }
            double xv[15];
            #pragma unroll
            for (int i = 0; i < 15; ++i) xv[i] = (double)cur[i];

            const double* wk = &wlds[ic * 72];
            #pragma unroll
            for (int k = 0; k < 9; ++k) {
                int kh = k / 3, kw = k % 3;
                double2 wa = *(const double2*)&wk[k * 8 + 0];
                double2 wb2 = *(const double2*)&wk[k * 8 + 2];
                double2 wc = *(const double2*)&wk[k * 8 + 4];
                double2 wd = *(const double2*)&wk[k * 8 + 6];
                double x0 = xv[kh * 3 + kw];
                double x1 = xv[(kh + 2) * 3 + kw];
                acc0[0] = fma(x0, wa.x, acc0[0]);   acc1[0] = fma(x1, wa.x, acc1[0]);
                acc0[1] = fma(x0, wa.y, acc0[1]);   acc1[1] = fma(x1, wa.y, acc1[1]);
                acc0[2] = fma(x0, wb2.x, acc0[2]);  acc1[2] = fma(x1, wb2.x, acc1[2]);
                acc0[3] = fma(x0, wb2.y, acc0[3]);  acc1[3] = fma(x1, wb2.y, acc1[3]);
                acc0[4] = fma(x0, wc.x, acc0[4]);   acc1[4] = fma(x1, wc.x, acc1[4]);
                acc0[5] = fma(x0, wc.y, acc0[5]);   acc1[5] = fma(x1, wc.y, acc1[5]);
                acc0[6] = fma(x0, wd.x, acc0[6]);   acc1[6] = fma(x1, wd.x, acc1[6]);
                acc0[7] = fma(x0, wd.y, acc0[7]);   acc1[7] = fma(x1, wd.y, acc1[7]);
            }
            #pragma unroll
            for (int i = 0; i < 15; ++i) cur[i] = nxt[i];
        }

        #pragma unroll
        for (int j = 0; j < 8; ++j) {
            int idx0 = ((b * 64 + ocg * 8 + j) * 32 + oh0) * 32 + ow;
            part[(size_t)isp * 524288 + idx0]      = (float)acc0[j];
            part[(size_t)isp * 524288 + idx0 + 32] = (float)acc1[j];
        }
    } else {
        // ================= MFMA path (r8): ksp 4..7, 16 ic each =================
        float* swt = (float*)smem_d;           // [khw][icb][n(64)][lg(4)]; reused for transpose
        int mt  = bid2 & 15;                   // oh0 = 2*mt
        int b   = (bid2 >> 4) & 7;
        int ksp = 4 + (bid2 >> 7);             // slices 4..7

        int l   = tid & 63;
        int wv  = tid >> 6;
        int wm  = wv >> 1;
        int wn  = wv & 1;
        int lc  = l & 15;
        int lg  = l >> 4;

        // D-layout probe (r7-verified method)
        double ap = (double)lc;
        double bp = (l == 0) ? 1.0 : 0.0;
        f64x4 dpr = {0., 0., 0., 0.};
        dpr = __builtin_amdgcn_mfma_f64_16x16x4f64(ap, bp, dpr, 0, 0, 0);
        int row0[4];
        #pragma unroll
        for (int r = 0; r < 4; ++r)
            row0[r] = ((int)__shfl(dpr[r], (l & 0x30), 64)) & 15;

        for (int i = tid; i < 9216; i += 256) {
            int g   = i & 3;
            int n   = (i >> 2) & 63;
            int kic = i >> 8;
            int khw = kic >> 2;
            int icb = kic & 3;
            swt[i] = w1[(n * 128 + ksp * 16 + icb * 4 + g) * 9 + khw];
        }
        __syncthreads();

        f64x4 d00 = {0., 0., 0., 0.}, d01 = {0., 0., 0., 0.};
        f64x4 d10 = {0., 0., 0., 0.}, d11 = {0., 0., 0., 0.};

        const float* cb = in + (size_t)(b * 128 + ksp * 16 + lg) * 4096;
        int r0 = 4 * mt + 2 * wm - 1;
        const float* pbase = cb + (ptrdiff_t)(r0 * 64 + 2 * lc - 1);
        bool c0ok = (lc != 0);
        const float* pB = swt + (wn * 32 + lc) * 4 + lg;

        #pragma unroll
        for (int khw = 0; khw < 9; ++khw) {
            const int kh = khw / 3;
            const int kw = khw - 3 * kh;
            bool rowok = (kh > 0) || (r0 >= 0);
            #pragma unroll
            for (int icb = 0; icb < 4; ++icb) {
                const int offA = icb * 16384 + kh * 64 + kw;
                bool ok0 = rowok && ((kw > 0) || c0ok);
                const float* q0 = ok0 ? (pbase + offA) : cb;
                float f0 = *q0;
                double a0 = ok0 ? (double)f0 : 0.0;
                const float* q1 = rowok ? (pbase + offA + 32) : cb;
                float f1 = *q1;
                double a1 = rowok ? (double)f1 : 0.0;

                const int offB = (khw * 4 + icb) * 256;
                double b0 = (double)pB[offB];
                double b1 = (double)pB[offB + 64];

                d00 = __builtin_amdgcn_mfma_f64_16x16x4f64(a0, b0, d00, 0, 0, 0);
                d01 = __builtin_amdgcn_mfma_f64_16x16x4f64(a0, b1, d01, 0, 0, 0);
                d10 = __builtin_amdgcn_mfma_f64_16x16x4f64(a1, b0, d10, 0, 0, 0);
                d11 = __builtin_amdgcn_mfma_f64_16x16x4f64(a1, b1, d11, 0, 0, 0);
            }
        }

        __syncthreads();
        float* so = (float*)smem_d;            // 64 oc x 66 = 4224 floats
        #pragma unroll
        for (int mi = 0; mi < 2; ++mi) {
            f64x4 v0 = mi ? d10 : d00;
            f64x4 v1 = mi ? d11 : d01;
            #pragma unroll
            for (int r = 0; r < 4; ++r) {
                int m   = wm * 32 + mi * 16 + row0[r];
                int oc0 = wn * 32 + lc;
                so[oc0 * 66 + m]        = (float)v0[r];
                so[(oc0 + 16) * 66 + m] = (float)v1[r];
            }
        }
        __syncthreads();
        int oh0 = 2 * mt;
        for (int i = tid; i < 4096; i += 256) {
            int oc = i >> 6;
            int m  = i & 63;
            part[(size_t)ksp * 524288 +
                 ((b * 64 + oc) * 32 + oh0 + (m >> 5)) * 32 + (m & 31)] = so[oc * 66 + m];
        }
    }
}

// ============ conv2 partial, FUSED with conv1-combine (sum 8 partials + BN1 + ReLU) =========
// grid 512 = isp(16: 4 ic) x b(8) x ocg(4); block 256 = full 16x16 spatial
__global__ __launch_bounds__(256) void conv2_partial_kernel(
    const float* __restrict__ part1,
    const float* __restrict__ g1, const float* __restrict__ be1,
    const float* __restrict__ mn1, const float* __restrict__ vr1,
    const float* __restrict__ w,
    float* __restrict__ part)
{
    __shared__ float tin[4][33][36];
    __shared__ float twt[4][9][8];
    __shared__ double sinv[4], ssh[4];

    int bid = blockIdx.x;
    int ocg = bid & 3;
    int b   = (bid >> 2) & 7;
    int isp = bid >> 5;

    int tid = threadIdx.x;
    int ow  = tid & 15;
    int oh  = tid >> 4;

    if (tid < 4) {
        int ch = isp * 4 + tid;
        double inv = (double)g1[ch] / sqrt((double)vr1[ch] + BN_EPS);
        sinv[tid] = inv;
        ssh[tid]  = (double)be1[ch] - (double)mn1[ch] * inv;
    }
    __syncthreads();

    for (int lin = tid; lin < 4 * 33 * 34; lin += 256) {
        int c   = lin % 34;
        int t2  = lin / 34;
        int rr  = t2 % 33;
        int icc = t2 / 33;
        int ih  = rr - 1;
        int iw  = c - 1;
        float v = 0.f;
        if ((unsigned)ih < 32u && (unsigned)iw < 32u) {
            int ch  = isp * 4 + icc;
            int idx = ((b * 64 + ch) * 32 + ih) * 32 + iw;
            double s = 0.0;
            #pragma unroll
            for (int p = 0; p < 8; ++p) s += (double)part1[idx + p * 524288];
            double o = s * sinv[icc] + ssh[icc];
            v = fmaxf((float)o, 0.f);
        }
        tin[icc][rr][c] = v;
    }
    for (int i = tid; i < 288; i += 256) {
        int j   = i & 7;
        int k   = (i >> 3) % 9;
        int icc = i / 72;
        twt[icc][k][j] = w[(ocg * 8 + j) * 576 + (isp * 4 + icc) * 9 + k];
    }
    __syncthreads();

    double acc[8];
    #pragma unroll
    for (int j = 0; j < 8; ++j) acc[j] = 0.0;

    for (int icc = 0; icc < 4; ++icc) {
        double xv[9];
        #pragma unroll
        for (int kh = 0; kh < 3; ++kh)
            #pragma unroll
            for (int kw = 0; kw < 3; ++kw)
                xv[kh * 3 + kw] = (double)tin[icc][2 * oh + kh][2 * ow + kw];
        #pragma unroll
        for (int k = 0; k < 9; ++k) {
            float4 wa = *(const float4*)&twt[icc][k][0];
            float4 wb = *(const float4*)&twt[icc][k][4];
            acc[0] = fma(xv[k], (double)wa.x, acc[0]);
            acc[1] = fma(xv[k], (double)wa.y, acc[1]);
            acc[2] = fma(xv[k], (double)wa.z, acc[2]);
            acc[3] = fma(xv[k], (double)wa.w, acc[3]);
            acc[4] = fma(xv[k], (double)wb.x, acc[4]);
            acc[5] = fma(xv[k], (double)wb.y, acc[5]);
            acc[6] = fma(xv[k], (double)wb.z, acc[6]);
            acc[7] = fma(xv[k], (double)wb.w, acc[7]);
        }
    }
    int obase = ((b * 32 + ocg * 8) * 16 + oh) * 16 + ow;
    #pragma unroll
    for (int j = 0; j < 8; ++j)
        part[isp * 65536 + obase + j * 256] = (float)acc[j];
}

// ============ conv2 combine + BN + ReLU + spatial mean -> ybar[256] ============
__global__ __launch_bounds__(256) void conv2_combine_ybar_kernel(
    const float* __restrict__ part,
    const float* __restrict__ g, const float* __restrict__ be,
    const float* __restrict__ mn, const float* __restrict__ vr,
    double* __restrict__ ybar)
{
    __shared__ double sm[4];
    int j  = blockIdx.x;             // j = b*32 + oc
    int oc = j & 31;
    int t  = threadIdx.x;
    int idx = j * 256 + t;
    double s = 0.0;
    #pragma unroll
    for (int p = 0; p < 16; ++p) s += (double)part[idx + p * 65536];
    double inv = (double)g[oc] / sqrt((double)vr[oc] + BN_EPS);
    double o = s * inv + ((double)be[oc] - (double)mn[oc] * inv);
    double v = fmax(o, 0.0);
    #pragma unroll
    for (int off = 32; off > 0; off >>= 1) v += __shfl_down(v, off, 64);
    if ((t & 63) == 0) sm[t >> 6] = v;
    __syncthreads();
    if (t == 0) ybar[j] = (sm[0] + sm[1] + sm[2] + sm[3]) * (1.0 / 256.0);
}

// ============ centers: conv3(1x1)+BN folded with the spatial mean, fp64 ============
__global__ __launch_bounds__(64) void centers_kernel(
    const double* __restrict__ ybar, const float* __restrict__ w3,
    const float* __restrict__ g, const float* __restrict__ be,
    const float* __restrict__ mn, const float* __restrict__ vr,
    double* __restrict__ cen_ws, float* __restrict__ cen_out)
{
    int t = threadIdx.x;
    if (t < 48) {
        int b = t / 6;
        int k = t % 6;
        double acc = 0.0;
        for (int ic = 0; ic < 32; ++ic) acc = fma((double)w3[k * 32 + ic], ybar[b * 32 + ic], acc);
        double inv = (double)g[k] / sqrt((double)vr[k] + BN_EPS);
        double c = acc * inv + ((double)be[k] - (double)mn[k] * inv);
        cen_ws[t]  = c;
        cen_out[t] = (float)c;
    }
}

// ============ quantization: fp64 dist/argmin, fp32 softmax; float4 I/O ============
__global__ __launch_bounds__(256) void quant_kernel(
    const float* __restrict__ x, const double* __restrict__ centers,
    float* __restrict__ qbar, float* __restrict__ qsoft,
    float* __restrict__ qhard, float* __restrict__ sym)
{
    int vid = blockIdx.x * 256 + threadIdx.x;   // float4 index; 2^17 vecs per batch
    int b = vid >> 17;

    double c[6];
    float cf[6];
    #pragma unroll
    for (int k = 0; k < 6; ++k) { c[k] = centers[b * 6 + k]; cf[k] = (float)c[k]; }

    float4 xv = ((const float4*)x)[vid];
    float xs[4] = {xv.x, xv.y, xv.z, xv.w};
    float r_bar[4], r_soft[4], r_hard[4], r_sym[4];

    #pragma unroll
    for (int i = 0; i < 4; ++i) {
        double xx = (double)xs[i];
        double d[6];
        double dmin = 1e300;
        int amin = 0;
        #pragma unroll
        for (int k = 0; k < 6; ++k) {
            double t = xx - c[k];
            d[k] = t * t;
            if (d[k] < dmin) { dmin = d[k]; amin = k; }
        }
        float se = 0.f, sw = 0.f;
        #pragma unroll
        for (int k = 0; k < 6; ++k) {
            float e = __expf(SIGMA * (float)(dmin - d[k]));
            se += e;
            sw += e * cf[k];
        }
        float qs = sw / se;
        float qh = cf[amin];
        r_soft[i] = qs;
        r_hard[i] = qh;
        r_bar[i]  = qh;
        r_sym[i]  = (float)amin;
    }

    ((float4*)qbar)[vid]  = make_float4(r_bar[0],  r_bar[1],  r_bar[2],  r_bar[3]);
    ((float4*)qsoft)[vid] = make_float4(r_soft[0], r_soft[1], r_soft[2], r_soft[3]);
    ((float4*)qhard)[vid] = make_float4(r_hard[0], r_hard[1], r_hard[2], r_hard[3]);
    ((float4*)sym)[vid]   = make_float4(r_sym[0],  r_sym[1],  r_sym[2],  r_sym[3]);
}

extern "C" void kernel_launch(void* const* d_in, const int* in_sizes, int n_in,
                              void* d_out, int out_size, void* d_ws, size_t ws_size,
                              hipStream_t stream) {
    const float* x  = (const float*)d_in[0];
    const float* cf = (const float*)d_in[1];
    const float* w1 = (const float*)d_in[2];
    const float* g1 = (const float*)d_in[3];
    const float* b1 = (const float*)d_in[4];
    const float* m1 = (const float*)d_in[5];
    const float* v1 = (const float*)d_in[6];
    const float* w2 = (const float*)d_in[7];
    const float* g2 = (const float*)d_in[8];
    const float* b2 = (const float*)d_in[9];
    const float* m2 = (const float*)d_in[10];
    const float* v2 = (const float*)d_in[11];
    const float* w3 = (const float*)d_in[12];
    const float* g3 = (const float*)d_in[13];
    const float* b3 = (const float*)d_in[14];
    const float* m3 = (const float*)d_in[15];
    const float* v3 = (const float*)d_in[16];

    const int NELEM = 8 * 128 * 64 * 64;      // 4,194,304
    float* out   = (float*)d_out;
    float* qbar  = out;
    float* qsoft = out + (size_t)NELEM;
    float* qhard = out + (size_t)2 * NELEM;
    float* sym   = out + (size_t)3 * NELEM;
    float* cen_o = out + (size_t)4 * NELEM;

    char* ws = (char*)d_ws;
    float*  part1 = (float*)(ws);                        // 8 x 524288 f32 = 16 MB
    float*  part2 = (float*)(ws + 16777216);             // 16 x 65536 f32 = 4 MB
    double* yb    = (double*)(ws + 20971520);            // 256 f64
    double* cen   = (double*)(ws + 20973568);            // 48 f64   (~21 MB total)

    conv1_hybrid_kernel<<<1024, 256, 0, stream>>>(cf, w1, part1);
    conv2_partial_kernel<<<512, 256, 0, stream>>>(part1, g1, b1, m1, v1, w2, part2);
    conv2_combine_ybar_kernel<<<256, 256, 0, stream>>>(part2, g2, b2, m2, v2, yb);
    centers_kernel<<<1, 64, 0, stream>>>(yb, w3, g3, b3, m3, v3, cen, cen_o);
    quant_kernel<<<NELEM / 4 / 256, 256, 0, stream>>>(x, cen, qbar, qsoft, qhard, sym);
}

// Round 12
// 187.348 us; speedup vs baseline: 1.0288x; 1.0033x over previous
//
#include <hip/hip_runtime.h>
#include <math.h>

#define BN_EPS 1e-5
#define SIGMA 1.0f

typedef double f64x4 __attribute__((ext_vector_type(4)));

// ============ conv1 HYBRID v2: scalar-VALU blocks + fp64-MFMA blocks co-resident ============
// Slices isp 0..3: r1-proven scalar path (VALU fp64 FMA).  Slices 4..7: r8-proven MFMA path.
// TYPE BIT FIX (r11 post-mortem): blocks co-resident on one CU have bids spaced by 256;
// typ=(bid>>3)&1 aliased to CU parity (each CU single-type, zero overlap). typ=(bid>>8)&1
// makes the 4 co-resident blocks alternate scalar/MFMA -> 2+2 per CU, pipes overlap.
// Per-path code byte-identical to proven rounds -> part1 bit-identical.
__global__ __launch_bounds__(256, 4) void conv1_hybrid_kernel(
    const float* __restrict__ in, const float* __restrict__ w1,
    float* __restrict__ part)
{
    __shared__ double smem_d[4608];            // union: scalar wlds[1152] f64 / mfma swt[9216] f32

    int bid  = blockIdx.x;
    int typ  = (bid >> 8) & 1;                 // co-resident blocks (stride 256) alternate type
    int bid2 = ((bid >> 9) << 8) | (bid & 255);// 0..511 within type
    int tid  = threadIdx.x;

    if (typ == 0) {
        // ================= scalar path (r1): isp 0..3, 16 ic each =================
        double* wlds = smem_d;                 // [ic(16)][k(9)][j(8)]
        int oht = bid2 & 1;
        int b   = (bid2 >> 1) & 7;
        int isp = (bid2 >> 4) & 3;             // slices 0..3
        int ocg = bid2 >> 6;

        int ow  = tid & 31;
        int ohp = tid >> 5;                    // 0..7
        int oh0 = oht * 16 + ohp * 2;
        int ih0 = 2 * oh0 - 1;
        int iw0 = 2 * ow - 1;

        for (int i = tid; i < 1152; i += 256) {
            int j  = i & 7;
            int t  = i >> 3;
            int k  = t % 9;
            int ic = t / 9;
            wlds[i] = (double)w1[((ocg * 8 + j) * 128 + isp * 16 + ic) * 9 + k];
        }
        __syncthreads();

        double acc0[8], acc1[8];
        #pragma unroll
        for (int j = 0; j < 8; ++j) { acc0[j] = 0.0; acc1[j] = 0.0; }

        bool rowok[5], colok[3];
        #pragma unroll
        for (int t = 0; t < 5; ++t) rowok[t] = (ih0 + t) >= 0;
        #pragma unroll
        for (int t = 0; t < 3; ++t) colok[t] = (iw0 + t) >= 0;

        const float* base0 = in + ((size_t)(b * 128 + isp * 16) * 64 + ih0) * 64 + iw0;

        float cur[15];
        #pragma unroll
        for (int t = 0; t < 5; ++t)
            #pragma unroll
            for (int kw = 0; kw < 3; ++kw)
                cur[t * 3 + kw] = (rowok[t] && colok[kw]) ? base0[t * 64 + kw] : 0.f;

        for (int ic = 0; ic < 16; ++ic) {
            float nxt[15];
            if (ic + 1 < 16) {
                const float* basen = base0 + (size_t)(ic + 1) * 4096;
                #pragma unroll
                for (int t = 0; t < 5; ++t)
                    #pragma unroll
                    for (int kw = 0; kw < 3; ++kw)
                        nxt[t * 3 + kw] = (rowok[t] && colok[kw]) ? basen[t * 64 + kw] : 0.f;
            }
            double xv[15];
            #pragma unroll
            for (int i = 0; i < 15; ++i) xv[i] = (double)cur[i];

            const double* wk = &wlds[ic * 72];
            #pragma unroll
            for (int k = 0; k < 9; ++k) {
                int kh = k / 3, kw = k % 3;
                double2 wa = *(const double2*)&wk[k * 8 + 0];
                double2 wb2 = *(const double2*)&wk[k * 8 + 2];
                double2 wc = *(const double2*)&wk[k * 8 + 4];
                double2 wd = *(const double2*)&wk[k * 8 + 6];
                double x0 = xv[kh * 3 + kw];
                double x1 = xv[(kh + 2) * 3 + kw];
                acc0[0] = fma(x0, wa.x, acc0[0]);   acc1[0] = fma(x1, wa.x, acc1[0]);
                acc0[1] = fma(x0, wa.y, acc0[1]);   acc1[1] = fma(x1, wa.y, acc1[1]);
                acc0[2] = fma(x0, wb2.x, acc0[2]);  acc1[2] = fma(x1, wb2.x, acc1[2]);
                acc0[3] = fma(x0, wb2.y, acc0[3]);  acc1[3] = fma(x1, wb2.y, acc1[3]);
                acc0[4] = fma(x0, wc.x, acc0[4]);   acc1[4] = fma(x1, wc.x, acc1[4]);
                acc0[5] = fma(x0, wc.y, acc0[5]);   acc1[5] = fma(x1, wc.y, acc1[5]);
                acc0[6] = fma(x0, wd.x, acc0[6]);   acc1[6] = fma(x1, wd.x, acc1[6]);
                acc0[7] = fma(x0, wd.y, acc0[7]);   acc1[7] = fma(x1, wd.y, acc1[7]);
            }
            #pragma unroll
            for (int i = 0; i < 15; ++i) cur[i] = nxt[i];
        }

        #pragma unroll
        for (int j = 0; j < 8; ++j) {
            int idx0 = ((b * 64 + ocg * 8 + j) * 32 + oh0) * 32 + ow;
            part[(size_t)isp * 524288 + idx0]      = (float)acc0[j];
            part[(size_t)isp * 524288 + idx0 + 32] = (float)acc1[j];
        }
    } else {
        // ================= MFMA path (r8): ksp 4..7, 16 ic each =================
        float* swt = (float*)smem_d;           // [khw][icb][n(64)][lg(4)]; reused for transpose
        int mt  = bid2 & 15;                   // oh0 = 2*mt
        int b   = (bid2 >> 4) & 7;
        int ksp = 4 + (bid2 >> 7);             // slices 4..7

        int l   = tid & 63;
        int wv  = tid >> 6;
        int wm  = wv >> 1;
        int wn  = wv & 1;
        int lc  = l & 15;
        int lg  = l >> 4;

        // D-layout probe (r7-verified method)
        double ap = (double)lc;
        double bp = (l == 0) ? 1.0 : 0.0;
        f64x4 dpr = {0., 0., 0., 0.};
        dpr = __builtin_amdgcn_mfma_f64_16x16x4f64(ap, bp, dpr, 0, 0, 0);
        int row0[4];
        #pragma unroll
        for (int r = 0; r < 4; ++r)
            row0[r] = ((int)__shfl(dpr[r], (l & 0x30), 64)) & 15;

        for (int i = tid; i < 9216; i += 256) {
            int g   = i & 3;
            int n   = (i >> 2) & 63;
            int kic = i >> 8;
            int khw = kic >> 2;
            int icb = kic & 3;
            swt[i] = w1[(n * 128 + ksp * 16 + icb * 4 + g) * 9 + khw];
        }
        __syncthreads();

        f64x4 d00 = {0., 0., 0., 0.}, d01 = {0., 0., 0., 0.};
        f64x4 d10 = {0., 0., 0., 0.}, d11 = {0., 0., 0., 0.};

        const float* cb = in + (size_t)(b * 128 + ksp * 16 + lg) * 4096;
        int r0 = 4 * mt + 2 * wm - 1;
        const float* pbase = cb + (ptrdiff_t)(r0 * 64 + 2 * lc - 1);
        bool c0ok = (lc != 0);
        const float* pB = swt + (wn * 32 + lc) * 4 + lg;

        #pragma unroll
        for (int khw = 0; khw < 9; ++khw) {
            const int kh = khw / 3;
            const int kw = khw - 3 * kh;
            bool rowok = (kh > 0) || (r0 >= 0);
            #pragma unroll
            for (int icb = 0; icb < 4; ++icb) {
                const int offA = icb * 16384 + kh * 64 + kw;
                bool ok0 = rowok && ((kw > 0) || c0ok);
                const float* q0 = ok0 ? (pbase + offA) : cb;
                float f0 = *q0;
                double a0 = ok0 ? (double)f0 : 0.0;
                const float* q1 = rowok ? (pbase + offA + 32) : cb;
                float f1 = *q1;
                double a1 = rowok ? (double)f1 : 0.0;

                const int offB = (khw * 4 + icb) * 256;
                double b0 = (double)pB[offB];
                double b1 = (double)pB[offB + 64];

                d00 = __builtin_amdgcn_mfma_f64_16x16x4f64(a0, b0, d00, 0, 0, 0);
                d01 = __builtin_amdgcn_mfma_f64_16x16x4f64(a0, b1, d01, 0, 0, 0);
                d10 = __builtin_amdgcn_mfma_f64_16x16x4f64(a1, b0, d10, 0, 0, 0);
                d11 = __builtin_amdgcn_mfma_f64_16x16x4f64(a1, b1, d11, 0, 0, 0);
            }
        }

        __syncthreads();
        float* so = (float*)smem_d;            // 64 oc x 66 = 4224 floats
        #pragma unroll
        for (int mi = 0; mi < 2; ++mi) {
            f64x4 v0 = mi ? d10 : d00;
            f64x4 v1 = mi ? d11 : d01;
            #pragma unroll
            for (int r = 0; r < 4; ++r) {
                int m   = wm * 32 + mi * 16 + row0[r];
                int oc0 = wn * 32 + lc;
                so[oc0 * 66 + m]        = (float)v0[r];
                so[(oc0 + 16) * 66 + m] = (float)v1[r];
            }
        }
        __syncthreads();
        int oh0 = 2 * mt;
        for (int i = tid; i < 4096; i += 256) {
            int oc = i >> 6;
            int m  = i & 63;
            part[(size_t)ksp * 524288 +
                 ((b * 64 + oc) * 32 + oh0 + (m >> 5)) * 32 + (m & 31)] = so[oc * 66 + m];
        }
    }
}

// ============ conv2 partial, FUSED with conv1-combine (sum 8 partials + BN1 + ReLU) =========
// grid 512 = isp(16: 4 ic) x b(8) x ocg(4); block 256 = full 16x16 spatial
__global__ __launch_bounds__(256) void conv2_partial_kernel(
    const float* __restrict__ part1,
    const float* __restrict__ g1, const float* __restrict__ be1,
    const float* __restrict__ mn1, const float* __restrict__ vr1,
    const float* __restrict__ w,
    float* __restrict__ part)
{
    __shared__ float tin[4][33][36];
    __shared__ float twt[4][9][8];
    __shared__ double sinv[4], ssh[4];

    int bid = blockIdx.x;
    int ocg = bid & 3;
    int b   = (bid >> 2) & 7;
    int isp = bid >> 5;

    int tid = threadIdx.x;
    int ow  = tid & 15;
    int oh  = tid >> 4;

    if (tid < 4) {
        int ch = isp * 4 + tid;
        double inv = (double)g1[ch] / sqrt((double)vr1[ch] + BN_EPS);
        sinv[tid] = inv;
        ssh[tid]  = (double)be1[ch] - (double)mn1[ch] * inv;
    }
    __syncthreads();

    for (int lin = tid; lin < 4 * 33 * 34; lin += 256) {
        int c   = lin % 34;
        int t2  = lin / 34;
        int rr  = t2 % 33;
        int icc = t2 / 33;
        int ih  = rr - 1;
        int iw  = c - 1;
        float v = 0.f;
        if ((unsigned)ih < 32u && (unsigned)iw < 32u) {
            int ch  = isp * 4 + icc;
            int idx = ((b * 64 + ch) * 32 + ih) * 32 + iw;
            double s = 0.0;
            #pragma unroll
            for (int p = 0; p < 8; ++p) s += (double)part1[idx + p * 524288];
            double o = s * sinv[icc] + ssh[icc];
            v = fmaxf((float)o, 0.f);
        }
        tin[icc][rr][c] = v;
    }
    for (int i = tid; i < 288; i += 256) {
        int j   = i & 7;
        int k   = (i >> 3) % 9;
        int icc = i / 72;
        twt[icc][k][j] = w[(ocg * 8 + j) * 576 + (isp * 4 + icc) * 9 + k];
    }
    __syncthreads();

    double acc[8];
    #pragma unroll
    for (int j = 0; j < 8; ++j) acc[j] = 0.0;

    for (int icc = 0; icc < 4; ++icc) {
        double xv[9];
        #pragma unroll
        for (int kh = 0; kh < 3; ++kh)
            #pragma unroll
            for (int kw = 0; kw < 3; ++kw)
                xv[kh * 3 + kw] = (double)tin[icc][2 * oh + kh][2 * ow + kw];
        #pragma unroll
        for (int k = 0; k < 9; ++k) {
            float4 wa = *(const float4*)&twt[icc][k][0];
            float4 wb = *(const float4*)&twt[icc][k][4];
            acc[0] = fma(xv[k], (double)wa.x, acc[0]);
            acc[1] = fma(xv[k], (double)wa.y, acc[1]);
            acc[2] = fma(xv[k], (double)wa.z, acc[2]);
            acc[3] = fma(xv[k], (double)wa.w, acc[3]);
            acc[4] = fma(xv[k], (double)wb.x, acc[4]);
            acc[5] = fma(xv[k], (double)wb.y, acc[5]);
            acc[6] = fma(xv[k], (double)wb.z, acc[6]);
            acc[7] = fma(xv[k], (double)wb.w, acc[7]);
        }
    }
    int obase = ((b * 32 + ocg * 8) * 16 + oh) * 16 + ow;
    #pragma unroll
    for (int j = 0; j < 8; ++j)
        part[isp * 65536 + obase + j * 256] = (float)acc[j];
}

// ============ conv2 combine + BN + ReLU + spatial mean -> ybar[256] ============
__global__ __launch_bounds__(256) void conv2_combine_ybar_kernel(
    const float* __restrict__ part,
    const float* __restrict__ g, const float* __restrict__ be,
    const float* __restrict__ mn, const float* __restrict__ vr,
    double* __restrict__ ybar)
{
    __shared__ double sm[4];
    int j  = blockIdx.x;             // j = b*32 + oc
    int oc = j & 31;
    int t  = threadIdx.x;
    int idx = j * 256 + t;
    double s = 0.0;
    #pragma unroll
    for (int p = 0; p < 16; ++p) s += (double)part[idx + p * 65536];
    double inv = (double)g[oc] / sqrt((double)vr[oc] + BN_EPS);
    double o = s * inv + ((double)be[oc] - (double)mn[oc] * inv);
    double v = fmax(o, 0.0);
    #pragma unroll
    for (int off = 32; off > 0; off >>= 1) v += __shfl_down(v, off, 64);
    if ((t & 63) == 0) sm[t >> 6] = v;
    __syncthreads();
    if (t == 0) ybar[j] = (sm[0] + sm[1] + sm[2] + sm[3]) * (1.0 / 256.0);
}

// ============ centers: conv3(1x1)+BN folded with the spatial mean, fp64 ============
__global__ __launch_bounds__(64) void centers_kernel(
    const double* __restrict__ ybar, const float* __restrict__ w3,
    const float* __restrict__ g, const float* __restrict__ be,
    const float* __restrict__ mn, const float* __restrict__ vr,
    double* __restrict__ cen_ws, float* __restrict__ cen_out)
{
    int t = threadIdx.x;
    if (t < 48) {
        int b = t / 6;
        int k = t % 6;
        double acc = 0.0;
        for (int ic = 0; ic < 32; ++ic) acc = fma((double)w3[k * 32 + ic], ybar[b * 32 + ic], acc);
        double inv = (double)g[k] / sqrt((double)vr[k] + BN_EPS);
        double c = acc * inv + ((double)be[k] - (double)mn[k] * inv);
        cen_ws[t]  = c;
        cen_out[t] = (float)c;
    }
}

// ============ quantization: fp64 dist/argmin, fp32 softmax; float4 I/O ============
__global__ __launch_bounds__(256) void quant_kernel(
    const float* __restrict__ x, const double* __restrict__ centers,
    float* __restrict__ qbar, float* __restrict__ qsoft,
    float* __restrict__ qhard, float* __restrict__ sym)
{
    int vid = blockIdx.x * 256 + threadIdx.x;   // float4 index; 2^17 vecs per batch
    int b = vid >> 17;

    double c[6];
    float cf[6];
    #pragma unroll
    for (int k = 0; k < 6; ++k) { c[k] = centers[b * 6 + k]; cf[k] = (float)c[k]; }

    float4 xv = ((const float4*)x)[vid];
    float xs[4] = {xv.x, xv.y, xv.z, xv.w};
    float r_bar[4], r_soft[4], r_hard[4], r_sym[4];

    #pragma unroll
    for (int i = 0; i < 4; ++i) {
        double xx = (double)xs[i];
        double d[6];
        double dmin = 1e300;
        int amin = 0;
        #pragma unroll
        for (int k = 0; k < 6; ++k) {
            double t = xx - c[k];
            d[k] = t * t;
            if (d[k] < dmin) { dmin = d[k]; amin = k; }
        }
        float se = 0.f, sw = 0.f;
        #pragma unroll
        for (int k = 0; k < 6; ++k) {
            float e = __expf(SIGMA * (float)(dmin - d[k]));
            se += e;
            sw += e * cf[k];
        }
        float qs = sw / se;
        float qh = cf[amin];
        r_soft[i] = qs;
        r_hard[i] = qh;
        r_bar[i]  = qh;
        r_sym[i]  = (float)amin;
    }

    ((float4*)qbar)[vid]  = make_float4(r_bar[0],  r_bar[1],  r_bar[2],  r_bar[3]);
    ((float4*)qsoft)[vid] = make_float4(r_soft[0], r_soft[1], r_soft[2], r_soft[3]);
    ((float4*)qhard)[vid] = make_float4(r_hard[0], r_hard[1], r_hard[2], r_hard[3]);
    ((float4*)sym)[vid]   = make_float4(r_sym[0],  r_sym[1],  r_sym[2],  r_sym[3]);
}

extern "C" void kernel_launch(void* const* d_in, const int* in_sizes, int n_in,
                              void* d_out, int out_size, void* d_ws, size_t ws_size,
                              hipStream_t stream) {
    const float* x  = (const float*)d_in[0];
    const float* cf = (const float*)d_in[1];
    const float* w1 = (const float*)d_in[2];
    const float* g1 = (const float*)d_in[3];
    const float* b1 = (const float*)d_in[4];
    const float* m1 = (const float*)d_in[5];
    const float* v1 = (const float*)d_in[6];
    const float* w2 = (const float*)d_in[7];
    const float* g2 = (const float*)d_in[8];
    const float* b2 = (const float*)d_in[9];
    const float* m2 = (const float*)d_in[10];
    const float* v2 = (const float*)d_in[11];
    const float* w3 = (const float*)d_in[12];
    const float* g3 = (const float*)d_in[13];
    const float* b3 = (const float*)d_in[14];
    const float* m3 = (const float*)d_in[15];
    const float* v3 = (const float*)d_in[16];

    const int NELEM = 8 * 128 * 64 * 64;      // 4,194,304
    float* out   = (float*)d_out;
    float* qbar  = out;
    float* qsoft = out + (size_t)NELEM;
    float* qhard = out + (size_t)2 * NELEM;
    float* sym   = out + (size_t)3 * NELEM;
    float* cen_o = out + (size_t)4 * NELEM;

    char* ws = (char*)d_ws;
    float*  part1 = (float*)(ws);                        // 8 x 524288 f32 = 16 MB
    float*  part2 = (float*)(ws + 16777216);             // 16 x 65536 f32 = 4 MB
    double* yb    = (double*)(ws + 20971520);            // 256 f64
    double* cen   = (double*)(ws + 20973568);            // 48 f64   (~21 MB total)

    conv1_hybrid_kernel<<<1024, 256, 0, stream>>>(cf, w1, part1);
    conv2_partial_kernel<<<512, 256, 0, stream>>>(part1, g1, b1, m1, v1, w2, part2);
    conv2_combine_ybar_kernel<<<256, 256, 0, stream>>>(part2, g2, b2, m2, v2, yb);
    centers_kernel<<<1, 64, 0, stream>>>(yb, w3, g3, b3, m3, v3, cen, cen_o);
    quant_kernel<<<NELEM / 4 / 256, 256, 0, stream>>>(x, cen, qbar, qsoft, qhard, sym);
}

// Round 13
// 185.194 us; speedup vs baseline: 1.0408x; 1.0116x over previous
//
#include <hip/hip_runtime.h>
#include <math.h>

#define BN_EPS 1e-5
#define SIGMA 1.0f

typedef double f64x4 __attribute__((ext_vector_type(4)));

// ============ conv1 via fp64 MFMA implicit GEMM (v5: TRUE 8 blocks/CU) ============
// r10 retry, deconfounded: grid 2048 (= 8 blocks/CU on 256 CUs) with HALF the work per
// block (64m x 32n), LDS 18.4 KB. Per-CU MFMA-pipe work unchanged; 8 waves/SIMD of
// independent MFMA streams hide the 64-cy f64 MFMA latency that capped r8/r9 at 32% util.
// K-order (khw major, icb minor, lg k-slot) identical to r8 -> part1 bit-identical.
// D row map probed at runtime (r7-verified method).
__global__ __launch_bounds__(256, 8) void conv1_mfma_kernel(
    const float* __restrict__ in, const float* __restrict__ w1,
    float* __restrict__ part)
{
    __shared__ float swt[4608];   // [khw][icb][nn(32)][lg(4)] = 18.4 KB; reused for transpose

    int bid = blockIdx.x;
    int mt  = bid & 15;            // oh0 = 2*mt
    int ng  = (bid >> 4) & 1;      // oc half (stride-16 sibling: same XCD, shares input)
    int b   = (bid >> 5) & 7;
    int ksp = bid >> 8;            // 16 ic per split

    int tid = threadIdx.x;
    int l   = tid & 63;
    int wv  = tid >> 6;            // 0..3
    int wr  = wv >> 1;             // row within block (0..1)
    int wc  = wv & 1;              // col half (0..1)
    int lc  = l & 15;
    int lg  = l >> 4;              // 0..3 (k-slot)

    // ---- D-layout probe: A[m][k] = m, B = delta(k==0,n==0) => D[m][0] = m.
    double ap = (double)lc;
    double bp = (l == 0) ? 1.0 : 0.0;
    f64x4 dpr = {0., 0., 0., 0.};
    dpr = __builtin_amdgcn_mfma_f64_16x16x4f64(ap, bp, dpr, 0, 0, 0);
    int row0[4];
    #pragma unroll
    for (int r = 0; r < 4; ++r)
        row0[r] = ((int)__shfl(dpr[r], (l & 0x30), 64)) & 15;

    // ---- stage weights: swt[((khw*4+icb)*32 + nn)*4 + g] = w1[ng*32+nn][ksp*16+icb*4+g][khw]
    for (int i = tid; i < 4608; i += 256) {
        int g   = i & 3;
        int nn  = (i >> 2) & 31;
        int kic = i >> 7;           // khw*4 + icb
        int khw = kic >> 2;
        int icb = kic & 3;
        swt[i] = w1[((ng * 32 + nn) * 128 + ksp * 16 + icb * 4 + g) * 9 + khw];
    }
    __syncthreads();

    f64x4 d0 = {0., 0., 0., 0.}, d1 = {0., 0., 0., 0.};

    // A: lane pixel oh = 2*mt + wr, ow = wc*16 + lc; channel = ksp*16 + icb*4 + lg
    const float* cb = in + (size_t)(b * 128 + ksp * 16 + lg) * 4096;
    int oh = 2 * mt + wr;
    int ow = wc * 16 + lc;
    int r0 = 2 * oh - 1;                                // ih for kh==0 (>= -1, <= 61)
    const float* pbase = cb + (ptrdiff_t)(r0 * 64 + 2 * ow - 1);
    bool c0ok = (ow != 0);

    // B per-lane base: nn = lc (+16 for d1), k-slot = lg
    const float* pB = swt + lc * 4 + lg;

    #pragma unroll
    for (int khw = 0; khw < 9; ++khw) {
        const int kh = khw / 3;
        const int kw = khw - 3 * kh;
        bool rowok = (kh > 0) || (r0 >= 0);
        #pragma unroll
        for (int icb = 0; icb < 4; ++icb) {
            const int offA = icb * 16384 + kh * 64 + kw;
            bool ok0 = rowok && ((kw > 0) || c0ok);
            const float* q0 = ok0 ? (pbase + offA) : cb;        // cb always valid
            float f0 = *q0;
            double a = ok0 ? (double)f0 : 0.0;

            const int offB = (khw * 4 + icb) * 128;
            double b0 = (double)pB[offB];
            double b1 = (double)pB[offB + 64];

            d0 = __builtin_amdgcn_mfma_f64_16x16x4f64(a, b0, d0, 0, 0, 0);
            d1 = __builtin_amdgcn_mfma_f64_16x16x4f64(a, b1, d1, 0, 0, 0);
        }
    }

    __syncthreads();   // weights done; reuse swt as transpose buffer (32 x 66 = 2112 f32)
    float* so = swt;
    {
        int pcol = wc * 16;
        #pragma unroll
        for (int r = 0; r < 4; ++r) {
            int p = wr * 32 + pcol + row0[r];           // pixel within block
            so[lc * 66 + p]        = (float)d0[r];
            so[(lc + 16) * 66 + p] = (float)d1[r];
        }
    }
    __syncthreads();
    int oh0 = 2 * mt;
    for (int i = tid; i < 2048; i += 256) {
        int ocl = i >> 6;            // 0..31
        int p   = i & 63;            // row p>>5 (0..1), col p&31
        part[(size_t)ksp * 524288 +
             ((b * 64 + ng * 32 + ocl) * 32 + oh0 + (p >> 5)) * 32 + (p & 31)] =
            so[ocl * 66 + p];
    }
}

// ============ conv2 partial, FUSED with conv1-combine (sum 8 partials + BN1 + ReLU) =========
// grid 512 = isp(16: 4 ic) x b(8) x ocg(4); block 256 = full 16x16 spatial
__global__ __launch_bounds__(256) void conv2_partial_kernel(
    const float* __restrict__ part1,
    const float* __restrict__ g1, const float* __restrict__ be1,
    const float* __restrict__ mn1, const float* __restrict__ vr1,
    const float* __restrict__ w,
    float* __restrict__ part)
{
    __shared__ float tin[4][33][36];
    __shared__ float twt[4][9][8];
    __shared__ double sinv[4], ssh[4];

    int bid = blockIdx.x;
    int ocg = bid & 3;
    int b   = (bid >> 2) & 7;
    int isp = bid >> 5;

    int tid = threadIdx.x;
    int ow  = tid & 15;
    int oh  = tid >> 4;

    if (tid < 4) {
        int ch = isp * 4 + tid;
        double inv = (double)g1[ch] / sqrt((double)vr1[ch] + BN_EPS);
        sinv[tid] = inv;
        ssh[tid]  = (double)be1[ch] - (double)mn1[ch] * inv;
    }
    __syncthreads();

    for (int lin = tid; lin < 4 * 33 * 34; lin += 256) {
        int c   = lin % 34;
        int t2  = lin / 34;
        int rr  = t2 % 33;
        int icc = t2 / 33;
        int ih  = rr - 1;
        int iw  = c - 1;
        float v = 0.f;
        if ((unsigned)ih < 32u && (unsigned)iw < 32u) {
            int ch  = isp * 4 + icc;
            int idx = ((b * 64 + ch) * 32 + ih) * 32 + iw;
            double s = 0.0;
            #pragma unroll
            for (int p = 0; p < 8; ++p) s += (double)part1[idx + p * 524288];
            double o = s * sinv[icc] + ssh[icc];
            v = fmaxf((float)o, 0.f);
        }
        tin[icc][rr][c] = v;
    }
    for (int i = tid; i < 288; i += 256) {
        int j   = i & 7;
        int k   = (i >> 3) % 9;
        int icc = i / 72;
        twt[icc][k][j] = w[(ocg * 8 + j) * 576 + (isp * 4 + icc) * 9 + k];
    }
    __syncthreads();

    double acc[8];
    #pragma unroll
    for (int j = 0; j < 8; ++j) acc[j] = 0.0;

    for (int icc = 0; icc < 4; ++icc) {
        double xv[9];
        #pragma unroll
        for (int kh = 0; kh < 3; ++kh)
            #pragma unroll
            for (int kw = 0; kw < 3; ++kw)
                xv[kh * 3 + kw] = (double)tin[icc][2 * oh + kh][2 * ow + kw];
        #pragma unroll
        for (int k = 0; k < 9; ++k) {
            float4 wa = *(const float4*)&twt[icc][k][0];
            float4 wb = *(const float4*)&twt[icc][k][4];
            acc[0] = fma(xv[k], (double)wa.x, acc[0]);
            acc[1] = fma(xv[k], (double)wa.y, acc[1]);
            acc[2] = fma(xv[k], (double)wa.z, acc[2]);
            acc[3] = fma(xv[k], (double)wa.w, acc[3]);
            acc[4] = fma(xv[k], (double)wb.x, acc[4]);
            acc[5] = fma(xv[k], (double)wb.y, acc[5]);
            acc[6] = fma(xv[k], (double)wb.z, acc[6]);
            acc[7] = fma(xv[k], (double)wb.w, acc[7]);
        }
    }
    int obase = ((b * 32 + ocg * 8) * 16 + oh) * 16 + ow;
    #pragma unroll
    for (int j = 0; j < 8; ++j)
        part[isp * 65536 + obase + j * 256] = (float)acc[j];
}

// ============ conv2 combine + BN + ReLU + spatial mean -> ybar[256] ============
__global__ __launch_bounds__(256) void conv2_combine_ybar_kernel(
    const float* __restrict__ part,
    const float* __restrict__ g, const float* __restrict__ be,
    const float* __restrict__ mn, const float* __restrict__ vr,
    double* __restrict__ ybar)
{
    __shared__ double sm[4];
    int j  = blockIdx.x;             // j = b*32 + oc
    int oc = j & 31;
    int t  = threadIdx.x;
    int idx = j * 256 + t;
    double s = 0.0;
    #pragma unroll
    for (int p = 0; p < 16; ++p) s += (double)part[idx + p * 65536];
    double inv = (double)g[oc] / sqrt((double)vr[oc] + BN_EPS);
    double o = s * inv + ((double)be[oc] - (double)mn[oc] * inv);
    double v = fmax(o, 0.0);
    #pragma unroll
    for (int off = 32; off > 0; off >>= 1) v += __shfl_down(v, off, 64);
    if ((t & 63) == 0) sm[t >> 6] = v;
    __syncthreads();
    if (t == 0) ybar[j] = (sm[0] + sm[1] + sm[2] + sm[3]) * (1.0 / 256.0);
}

// ============ centers: conv3(1x1)+BN folded with the spatial mean, fp64 ============
__global__ __launch_bounds__(64) void centers_kernel(
    const double* __restrict__ ybar, const float* __restrict__ w3,
    const float* __restrict__ g, const float* __restrict__ be,
    const float* __restrict__ mn, const float* __restrict__ vr,
    double* __restrict__ cen_ws, float* __restrict__ cen_out)
{
    int t = threadIdx.x;
    if (t < 48) {
        int b = t / 6;
        int k = t % 6;
        double acc = 0.0;
        for (int ic = 0; ic < 32; ++ic) acc = fma((double)w3[k * 32 + ic], ybar[b * 32 + ic], acc);
        double inv = (double)g[k] / sqrt((double)vr[k] + BN_EPS);
        double c = acc * inv + ((double)be[k] - (double)mn[k] * inv);
        cen_ws[t]  = c;
        cen_out[t] = (float)c;
    }
}

// ============ quantization: fp64 dist/argmin, fp32 softmax; float4 I/O ============
__global__ __launch_bounds__(256) void quant_kernel(
    const float* __restrict__ x, const double* __restrict__ centers,
    float* __restrict__ qbar, float* __restrict__ qsoft,
    float* __restrict__ qhard, float* __restrict__ sym)
{
    int vid = blockIdx.x * 256 + threadIdx.x;   // float4 index; 2^17 vecs per batch
    int b = vid >> 17;

    double c[6];
    float cf[6];
    #pragma unroll
    for (int k = 0; k < 6; ++k) { c[k] = centers[b * 6 + k]; cf[k] = (float)c[k]; }

    float4 xv = ((const float4*)x)[vid];
    float xs[4] = {xv.x, xv.y, xv.z, xv.w};
    float r_bar[4], r_soft[4], r_hard[4], r_sym[4];

    #pragma unroll
    for (int i = 0; i < 4; ++i) {
        double xx = (double)xs[i];
        double d[6];
        double dmin = 1e300;
        int amin = 0;
        #pragma unroll
        for (int k = 0; k < 6; ++k) {
            double t = xx - c[k];
            d[k] = t * t;
            if (d[k] < dmin) { dmin = d[k]; amin = k; }
        }
        float se = 0.f, sw = 0.f;
        #pragma unroll
        for (int k = 0; k < 6; ++k) {
            float e = __expf(SIGMA * (float)(dmin - d[k]));
            se += e;
            sw += e * cf[k];
        }
        float qs = sw / se;
        float qh = cf[amin];
        r_soft[i] = qs;
        r_hard[i] = qh;
        r_bar[i]  = qh;
        r_sym[i]  = (float)amin;
    }

    ((float4*)qbar)[vid]  = make_float4(r_bar[0],  r_bar[1],  r_bar[2],  r_bar[3]);
    ((float4*)qsoft)[vid] = make_float4(r_soft[0], r_soft[1], r_soft[2], r_soft[3]);
    ((float4*)qhard)[vid] = make_float4(r_hard[0], r_hard[1], r_hard[2], r_hard[3]);
    ((float4*)sym)[vid]   = make_float4(r_sym[0],  r_sym[1],  r_sym[2],  r_sym[3]);
}

extern "C" void kernel_launch(void* const* d_in, const int* in_sizes, int n_in,
                              void* d_out, int out_size, void* d_ws, size_t ws_size,
                              hipStream_t stream) {
    const float* x  = (const float*)d_in[0];
    const float* cf = (const float*)d_in[1];
    const float* w1 = (const float*)d_in[2];
    const float* g1 = (const float*)d_in[3];
    const float* b1 = (const float*)d_in[4];
    const float* m1 = (const float*)d_in[5];
    const float* v1 = (const float*)d_in[6];
    const float* w2 = (const float*)d_in[7];
    const float* g2 = (const float*)d_in[8];
    const float* b2 = (const float*)d_in[9];
    const float* m2 = (const float*)d_in[10];
    const float* v2 = (const float*)d_in[11];
    const float* w3 = (const float*)d_in[12];
    const float* g3 = (const float*)d_in[13];
    const float* b3 = (const float*)d_in[14];
    const float* m3 = (const float*)d_in[15];
    const float* v3 = (const float*)d_in[16];

    const int NELEM = 8 * 128 * 64 * 64;      // 4,194,304
    float* out   = (float*)d_out;
    float* qbar  = out;
    float* qsoft = out + (size_t)NELEM;
    float* qhard = out + (size_t)2 * NELEM;
    float* sym   = out + (size_t)3 * NELEM;
    float* cen_o = out + (size_t)4 * NELEM;

    char* ws = (char*)d_ws;
    float*  part1 = (float*)(ws);                        // 8 x 524288 f32 = 16 MB
    float*  part2 = (float*)(ws + 16777216);             // 16 x 65536 f32 = 4 MB
    double* yb    = (double*)(ws + 20971520);            // 256 f64
    double* cen   = (double*)(ws + 20973568);            // 48 f64   (~21 MB total)

    conv1_mfma_kernel<<<2048, 256, 0, stream>>>(cf, w1, part1);
    conv2_partial_kernel<<<512, 256, 0, stream>>>(part1, g1, b1, m1, v1, w2, part2);
    conv2_combine_ybar_kernel<<<256, 256, 0, stream>>>(part2, g2, b2, m2, v2, yb);
    centers_kernel<<<1, 64, 0, stream>>>(yb, w3, g3, b3, m3, v3, cen, cen_o);
    quant_kernel<<<NELEM / 4 / 256, 256, 0, stream>>>(x, cen, qbar, qsoft, qhard, sym);
}

// Round 14
// 182.486 us; speedup vs baseline: 1.0563x; 1.0148x over previous
//
#include <hip/hip_runtime.h>
#include <math.h>

#define BN_EPS 1e-5
#define SIGMA 1.0f

typedef double f64x4 __attribute__((ext_vector_type(4)));

// ============ conv1 via fp64 MFMA implicit GEMM (r13-frozen: DP-pipe floor ~40 us) ========
// Scalar-VALU and f64-MFMA variants both converge to ~40-44 us and the r12 hybrid was
// additive -> f64 MFMA and f64 VALU share the DP unit; this is the DP-op floor.
__global__ __launch_bounds__(256, 8) void conv1_mfma_kernel(
    const float* __restrict__ in, const float* __restrict__ w1,
    float* __restrict__ part)
{
    __shared__ float swt[4608];   // [khw][icb][nn(32)][lg(4)] = 18.4 KB; reused for transpose

    int bid = blockIdx.x;
    int mt  = bid & 15;            // oh0 = 2*mt
    int ng  = (bid >> 4) & 1;      // oc half
    int b   = (bid >> 5) & 7;
    int ksp = bid >> 8;            // 16 ic per split

    int tid = threadIdx.x;
    int l   = tid & 63;
    int wv  = tid >> 6;            // 0..3
    int wr  = wv >> 1;             // row within block (0..1)
    int wc  = wv & 1;              // col half (0..1)
    int lc  = l & 15;
    int lg  = l >> 4;              // 0..3 (k-slot)

    // ---- D-layout probe (r7-verified): A[m][k]=m, B=delta(k==0,n==0) => D[m][0]=m.
    double ap = (double)lc;
    double bp = (l == 0) ? 1.0 : 0.0;
    f64x4 dpr = {0., 0., 0., 0.};
    dpr = __builtin_amdgcn_mfma_f64_16x16x4f64(ap, bp, dpr, 0, 0, 0);
    int row0[4];
    #pragma unroll
    for (int r = 0; r < 4; ++r)
        row0[r] = ((int)__shfl(dpr[r], (l & 0x30), 64)) & 15;

    // ---- stage weights: swt[((khw*4+icb)*32 + nn)*4 + g] = w1[ng*32+nn][ksp*16+icb*4+g][khw]
    for (int i = tid; i < 4608; i += 256) {
        int g   = i & 3;
        int nn  = (i >> 2) & 31;
        int kic = i >> 7;           // khw*4 + icb
        int khw = kic >> 2;
        int icb = kic & 3;
        swt[i] = w1[((ng * 32 + nn) * 128 + ksp * 16 + icb * 4 + g) * 9 + khw];
    }
    __syncthreads();

    f64x4 d0 = {0., 0., 0., 0.}, d1 = {0., 0., 0., 0.};

    const float* cb = in + (size_t)(b * 128 + ksp * 16 + lg) * 4096;
    int oh = 2 * mt + wr;
    int ow = wc * 16 + lc;
    int r0 = 2 * oh - 1;                                // ih for kh==0 (>= -1, <= 61)
    const float* pbase = cb + (ptrdiff_t)(r0 * 64 + 2 * ow - 1);
    bool c0ok = (ow != 0);

    const float* pB = swt + lc * 4 + lg;

    #pragma unroll
    for (int khw = 0; khw < 9; ++khw) {
        const int kh = khw / 3;
        const int kw = khw - 3 * kh;
        bool rowok = (kh > 0) || (r0 >= 0);
        #pragma unroll
        for (int icb = 0; icb < 4; ++icb) {
            const int offA = icb * 16384 + kh * 64 + kw;
            bool ok0 = rowok && ((kw > 0) || c0ok);
            const float* q0 = ok0 ? (pbase + offA) : cb;        // cb always valid
            float f0 = *q0;
            double a = ok0 ? (double)f0 : 0.0;

            const int offB = (khw * 4 + icb) * 128;
            double b0 = (double)pB[offB];
            double b1 = (double)pB[offB + 64];

            d0 = __builtin_amdgcn_mfma_f64_16x16x4f64(a, b0, d0, 0, 0, 0);
            d1 = __builtin_amdgcn_mfma_f64_16x16x4f64(a, b1, d1, 0, 0, 0);
        }
    }

    __syncthreads();   // weights done; reuse swt as transpose buffer (32 x 66)
    float* so = swt;
    {
        int pcol = wc * 16;
        #pragma unroll
        for (int r = 0; r < 4; ++r) {
            int p = wr * 32 + pcol + row0[r];           // pixel within block
            so[lc * 66 + p]        = (float)d0[r];
            so[(lc + 16) * 66 + p] = (float)d1[r];
        }
    }
    __syncthreads();
    int oh0 = 2 * mt;
    for (int i = tid; i < 2048; i += 256) {
        int ocl = i >> 6;            // 0..31
        int p   = i & 63;            // row p>>5 (0..1), col p&31
        part[(size_t)ksp * 524288 +
             ((b * 64 + ng * 32 + ocl) * 32 + oh0 + (p >> 5)) * 32 + (p & 31)] =
            so[ocl * 66 + p];
    }
}

// ============ conv2 partial, FUSED with conv1-combine (sum 8 partials + BN1 + ReLU) =========
// grid 512 = isp(16: 4 ic) x b(8) x ocg(4); block 256 = full 16x16 spatial
__global__ __launch_bounds__(256) void conv2_partial_kernel(
    const float* __restrict__ part1,
    const float* __restrict__ g1, const float* __restrict__ be1,
    const float* __restrict__ mn1, const float* __restrict__ vr1,
    const float* __restrict__ w,
    float* __restrict__ part)
{
    __shared__ float tin[4][33][36];
    __shared__ float twt[4][9][8];
    __shared__ double sinv[4], ssh[4];

    int bid = blockIdx.x;
    int ocg = bid & 3;
    int b   = (bid >> 2) & 7;
    int isp = bid >> 5;

    int tid = threadIdx.x;
    int ow  = tid & 15;
    int oh  = tid >> 4;

    if (tid < 4) {
        int ch = isp * 4 + tid;
        double inv = (double)g1[ch] / sqrt((double)vr1[ch] + BN_EPS);
        sinv[tid] = inv;
        ssh[tid]  = (double)be1[ch] - (double)mn1[ch] * inv;
    }
    __syncthreads();

    for (int lin = tid; lin < 4 * 33 * 34; lin += 256) {
        int c   = lin % 34;
        int t2  = lin / 34;
        int rr  = t2 % 33;
        int icc = t2 / 33;
        int ih  = rr - 1;
        int iw  = c - 1;
        float v = 0.f;
        if ((unsigned)ih < 32u && (unsigned)iw < 32u) {
            int ch  = isp * 4 + icc;
            int idx = ((b * 64 + ch) * 32 + ih) * 32 + iw;
            double s = 0.0;
            #pragma unroll
            for (int p = 0; p < 8; ++p) s += (double)part1[idx + p * 524288];
            double o = s * sinv[icc] + ssh[icc];
            v = fmaxf((float)o, 0.f);
        }
        tin[icc][rr][c] = v;
    }
    for (int i = tid; i < 288; i += 256) {
        int j   = i & 7;
        int k   = (i >> 3) % 9;
        int icc = i / 72;
        twt[icc][k][j] = w[(ocg * 8 + j) * 576 + (isp * 4 + icc) * 9 + k];
    }
    __syncthreads();

    double acc[8];
    #pragma unroll
    for (int j = 0; j < 8; ++j) acc[j] = 0.0;

    for (int icc = 0; icc < 4; ++icc) {
        double xv[9];
        #pragma unroll
        for (int kh = 0; kh < 3; ++kh)
            #pragma unroll
            for (int kw = 0; kw < 3; ++kw)
                xv[kh * 3 + kw] = (double)tin[icc][2 * oh + kh][2 * ow + kw];
        #pragma unroll
        for (int k = 0; k < 9; ++k) {
            float4 wa = *(const float4*)&twt[icc][k][0];
            float4 wb = *(const float4*)&twt[icc][k][4];
            acc[0] = fma(xv[k], (double)wa.x, acc[0]);
            acc[1] = fma(xv[k], (double)wa.y, acc[1]);
            acc[2] = fma(xv[k], (double)wa.z, acc[2]);
            acc[3] = fma(xv[k], (double)wa.w, acc[3]);
            acc[4] = fma(xv[k], (double)wb.x, acc[4]);
            acc[5] = fma(xv[k], (double)wb.y, acc[5]);
            acc[6] = fma(xv[k], (double)wb.z, acc[6]);
            acc[7] = fma(xv[k], (double)wb.w, acc[7]);
        }
    }
    int obase = ((b * 32 + ocg * 8) * 16 + oh) * 16 + ow;
    #pragma unroll
    for (int j = 0; j < 8; ++j)
        part[isp * 65536 + obase + j * 256] = (float)acc[j];
}

// ============ conv2 combine + BN + ReLU + spatial mean -> ybar[256] ============
__global__ __launch_bounds__(256) void conv2_combine_ybar_kernel(
    const float* __restrict__ part,
    const float* __restrict__ g, const float* __restrict__ be,
    const float* __restrict__ mn, const float* __restrict__ vr,
    double* __restrict__ ybar)
{
    __shared__ double sm[4];
    int j  = blockIdx.x;             // j = b*32 + oc
    int oc = j & 31;
    int t  = threadIdx.x;
    int idx = j * 256 + t;
    double s = 0.0;
    #pragma unroll
    for (int p = 0; p < 16; ++p) s += (double)part[idx + p * 65536];
    double inv = (double)g[oc] / sqrt((double)vr[oc] + BN_EPS);
    double o = s * inv + ((double)be[oc] - (double)mn[oc] * inv);
    double v = fmax(o, 0.0);
    #pragma unroll
    for (int off = 32; off > 0; off >>= 1) v += __shfl_down(v, off, 64);
    if ((t & 63) == 0) sm[t >> 6] = v;
    __syncthreads();
    if (t == 0) ybar[j] = (sm[0] + sm[1] + sm[2] + sm[3]) * (1.0 / 256.0);
}

// ============ quantization, FUSED with centers (conv3 1x1 + BN on ybar) ============
// Each block serves one batch (512 blocks/batch); threads 0..5 compute the 6 centers
// in fp64 with op order IDENTICAL to the old centers_kernel -> bit-identical centers.
// Designated block per batch (blockIdx % 512 == 0) writes cen_out.
__global__ __launch_bounds__(256) void quant_kernel(
    const float* __restrict__ x, const double* __restrict__ ybar,
    const float* __restrict__ w3,
    const float* __restrict__ g, const float* __restrict__ be,
    const float* __restrict__ mn, const float* __restrict__ vr,
    float* __restrict__ qbar, float* __restrict__ qsoft,
    float* __restrict__ qhard, float* __restrict__ sym,
    float* __restrict__ cen_out)
{
    __shared__ double scen[6];

    int tid = threadIdx.x;
    int vid = blockIdx.x * 256 + tid;   // float4 index; 2^17 vecs per batch
    int b = blockIdx.x >> 9;            // 512 blocks per batch

    if (tid < 6) {
        int k = tid;
        double acc = 0.0;
        for (int ic = 0; ic < 32; ++ic)
            acc = fma((double)w3[k * 32 + ic], ybar[b * 32 + ic], acc);
        double inv = (double)g[k] / sqrt((double)vr[k] + BN_EPS);
        double c = acc * inv + ((double)be[k] - (double)mn[k] * inv);
        scen[k] = c;
        if ((blockIdx.x & 511) == 0) cen_out[b * 6 + k] = (float)c;
    }
    __syncthreads();

    double c[6];
    float cf[6];
    #pragma unroll
    for (int k = 0; k < 6; ++k) { c[k] = scen[k]; cf[k] = (float)c[k]; }

    float4 xv = ((const float4*)x)[vid];
    float xs[4] = {xv.x, xv.y, xv.z, xv.w};
    float r_bar[4], r_soft[4], r_hard[4], r_sym[4];

    #pragma unroll
    for (int i = 0; i < 4; ++i) {
        double xx = (double)xs[i];
        double d[6];
        double dmin = 1e300;
        int amin = 0;
        #pragma unroll
        for (int k = 0; k < 6; ++k) {
            double t = xx - c[k];
            d[k] = t * t;
            if (d[k] < dmin) { dmin = d[k]; amin = k; }
        }
        float se = 0.f, sw = 0.f;
        #pragma unroll
        for (int k = 0; k < 6; ++k) {
            float e = __expf(SIGMA * (float)(dmin - d[k]));
            se += e;
            sw += e * cf[k];
        }
        float qs = sw / se;
        float qh = cf[amin];
        r_soft[i] = qs;
        r_hard[i] = qh;
        r_bar[i]  = qh;
        r_sym[i]  = (float)amin;
    }

    ((float4*)qbar)[vid]  = make_float4(r_bar[0],  r_bar[1],  r_bar[2],  r_bar[3]);
    ((float4*)qsoft)[vid] = make_float4(r_soft[0], r_soft[1], r_soft[2], r_soft[3]);
    ((float4*)qhard)[vid] = make_float4(r_hard[0], r_hard[1], r_hard[2], r_hard[3]);
    ((float4*)sym)[vid]   = make_float4(r_sym[0],  r_sym[1],  r_sym[2],  r_sym[3]);
}

extern "C" void kernel_launch(void* const* d_in, const int* in_sizes, int n_in,
                              void* d_out, int out_size, void* d_ws, size_t ws_size,
                              hipStream_t stream) {
    const float* x  = (const float*)d_in[0];
    const float* cf = (const float*)d_in[1];
    const float* w1 = (const float*)d_in[2];
    const float* g1 = (const float*)d_in[3];
    const float* b1 = (const float*)d_in[4];
    const float* m1 = (const float*)d_in[5];
    const float* v1 = (const float*)d_in[6];
    const float* w2 = (const float*)d_in[7];
    const float* g2 = (const float*)d_in[8];
    const float* b2 = (const float*)d_in[9];
    const float* m2 = (const float*)d_in[10];
    const float* v2 = (const float*)d_in[11];
    const float* w3 = (const float*)d_in[12];
    const float* g3 = (const float*)d_in[13];
    const float* b3 = (const float*)d_in[14];
    const float* m3 = (const float*)d_in[15];
    const float* v3 = (const float*)d_in[16];

    const int NELEM = 8 * 128 * 64 * 64;      // 4,194,304
    float* out   = (float*)d_out;
    float* qbar  = out;
    float* qsoft = out + (size_t)NELEM;
    float* qhard = out + (size_t)2 * NELEM;
    float* sym   = out + (size_t)3 * NELEM;
    float* cen_o = out + (size_t)4 * NELEM;

    char* ws = (char*)d_ws;
    float*  part1 = (float*)(ws);                        // 8 x 524288 f32 = 16 MB
    float*  part2 = (float*)(ws + 16777216);             // 16 x 65536 f32 = 4 MB
    double* yb    = (double*)(ws + 20971520);            // 256 f64  (~21 MB total)

    conv1_mfma_kernel<<<2048, 256, 0, stream>>>(cf, w1, part1);
    conv2_partial_kernel<<<512, 256, 0, stream>>>(part1, g1, b1, m1, v1, w2, part2);
    conv2_combine_ybar_kernel<<<256, 256, 0, stream>>>(part2, g2, b2, m2, v2, yb);
    quant_kernel<<<NELEM / 4 / 256, 256, 0, stream>>>(x, yb, w3, g3, b3, m3, v3,
                                                      qbar, qsoft, qhard, sym, cen_o);
}